// Round 15
// baseline (655.044 us; speedup 1.0000x reference)
//
#include <hip/hip_runtime.h>

// VQ-VAE Vector Quantizer: N=65536 rows, K=4096 codes, D=64, fp32.
// R14: R13 + K-split occupancy fix. R13 PROVED the MFMA two-pass numerics
// (passed, absmax 0.0) but ran sweeps at grid=512 blocks = 2 waves/SIMD ->
// latency-exposed (Mfma 12.7%, VALU 15.3%, occ 22%; sweep 330us vs ~12us
// MFMA floor). Fix: split each sweep's K-range over blockIdx.y (4 slices of
// 1024 codes) -> 2048 blocks = 8 waves/SIMD at VGPR=64. sweep1 writes
// per-slice aminS[s][row]; sweep2 bands on fmin of the 4 (identical band).
// cand's lexicographic atomicMin is slice-order-independent -> identical
// indices. All numerics byte-identical to R13.
// Scheme recap: pass1 approx amin via mfma_f32_16x16x32_bf16 with bf16x2
// error-free split (6 products/k64); pass2 re-sweeps, codes with
// d <= amin+1e-4 get the BIT-EXACT R10 fp32 dist (same quad-split FMA
// sequence) + atomicMin on (dist_bits<<32|code) -> exact first-index argmin.
//
// out layout (float): [0,N*D) z_q_st | [ND] vq | [ND+1] cb | [ND+2] cm |
//                     [ND+3, ND+3+N) indices | [ND+3+N] perplexity | [ND+4+N] active

constexpr int N = 65536;
constexpr int K = 4096;
constexpr int D = 64;
constexpr int SL = 4;        // K-split for the sweeps
constexpr int KSL = K / SL;  // 1024 codes per slice
constexpr int TS = KSL / 16; // 64 iterations per slice

typedef short s8v __attribute__((ext_vector_type(8)));   // 8 bf16 (4 VGPRs)
typedef float f4 __attribute__((ext_vector_type(4)));    // 4 fp32 acc

#define MFMA(a, b, c) __builtin_amdgcn_mfma_f32_16x16x32_bf16((a), (b), (c), 0, 0, 0)

__device__ inline unsigned bfr(float x) {  // fp32 -> bf16 bits, RNE
  unsigned b = __float_as_uint(x);
  return (b + 0x7FFFu + ((b >> 16) & 1u)) >> 16;
}

__device__ inline void splitbf(const float4 v0, const float4 v1, s8v& hi, s8v& lo) {
  float x[8] = {v0.x, v0.y, v0.z, v0.w, v1.x, v1.y, v1.z, v1.w};
#pragma unroll
  for (int j = 0; j < 8; ++j) {
    unsigned h = bfr(x[j]);
    float hf = __uint_as_float(h << 16);
    unsigned l = bfr(x[j] - hf);
    hi[j] = (short)h;
    lo[j] = (short)l;
  }
}

// prep: e2 (exact quad-split, same as R10), counts=0, loss=0, bf16x2 split of emb.
__global__ __launch_bounds__(256) void prep_emb(const float* __restrict__ emb,
                                                float* __restrict__ e2,
                                                int* __restrict__ counts,
                                                float* __restrict__ loss,
                                                unsigned short* __restrict__ eh,
                                                unsigned short* __restrict__ el) {
  int k = blockIdx.x * 256 + threadIdx.x;
  if (k < K) {
    const float4* ep = (const float4*)(emb + (size_t)k * D);
    unsigned short* ehr = eh + (size_t)k * D;
    unsigned short* elr = el + (size_t)k * D;
    float s0 = 0.f, s1 = 0.f, s2 = 0.f, s3 = 0.f;
#pragma unroll
    for (int i = 0; i < 16; ++i) {
      float4 e = ep[i];
      s0 = fmaf(e.x, e.x, s0);
      s1 = fmaf(e.y, e.y, s1);
      s2 = fmaf(e.z, e.z, s2);
      s3 = fmaf(e.w, e.w, s3);
      float xs[4] = {e.x, e.y, e.z, e.w};
#pragma unroll
      for (int c = 0; c < 4; ++c) {
        unsigned h = bfr(xs[c]);
        ehr[4 * i + c] = (unsigned short)h;
        elr[4 * i + c] = (unsigned short)bfr(xs[c] - __uint_as_float(h << 16));
      }
    }
    e2[k] = (s0 + s1) + (s2 + s3);
    counts[k] = 0;
  }
  if (blockIdx.x == 0 && threadIdx.x == 0) *loss = 0.0f;
}

// prep: z2 per row (exact quad-split, bit-identical to R10's in-kernel z2) + cand init.
__global__ __launch_bounds__(256) void prep_z(const float* __restrict__ z,
                                              float* __restrict__ z2,
                                              unsigned long long* __restrict__ cand) {
  int n = blockIdx.x * 256 + threadIdx.x;
  const float4* zp = (const float4*)(z + (size_t)n * D);
  float s0 = 0.f, s1 = 0.f, s2 = 0.f, s3 = 0.f;
#pragma unroll
  for (int i = 0; i < 16; ++i) {
    float4 v = zp[i];
    s0 = fmaf(v.x, v.x, s0);
    s1 = fmaf(v.y, v.y, s1);
    s2 = fmaf(v.z, v.z, s2);
    s3 = fmaf(v.w, v.w, s3);
  }
  z2[n] = (s0 + s1) + (s2 + s3);
  cand[n] = 0x7F800000FFFFFFFFull;  // (+inf bits, idx max)
}

// Pass 1: approx dist sweep via MFMA over one K-slice; per-(slice,row) min.
// Block = 4 waves; wave owns 2 row-tiles (32 rows); grid = (N/128, SL).
__global__ __launch_bounds__(256) void sweep1(const float* __restrict__ z,
                                              const float* __restrict__ z2g,
                                              const float* __restrict__ e2,
                                              const unsigned short* __restrict__ eh,
                                              const unsigned short* __restrict__ el,
                                              float* __restrict__ aminS) {
  const int tid = threadIdx.x;
  const int lane = tid & 63;
  const int wv = tid >> 6;
  const int g = lane >> 4;
  const int c15 = lane & 15;
  const int rowbase = blockIdx.x * 128 + wv * 32;
  const int s = blockIdx.y;
  const int k0 = s * KSL;

  // A fragments: z rows (lane&15 selects row), k = 32c + 8g + j, bf16x2 split.
  s8v Ah[2][2], Al[2][2];
#pragma unroll
  for (int rt = 0; rt < 2; ++rt) {
    const float* zrow = z + (size_t)(rowbase + rt * 16 + c15) * D;
#pragma unroll
    for (int c = 0; c < 2; ++c) {
      float4 v0 = *(const float4*)(zrow + c * 32 + g * 8);
      float4 v1 = *(const float4*)(zrow + c * 32 + g * 8 + 4);
      splitbf(v0, v1, Ah[rt][c], Al[rt][c]);
    }
  }
  // z2 for the rows this lane's acc covers: row = rowbase + rt*16 + g*4 + r.
  float z2r[2][4];
#pragma unroll
  for (int rt = 0; rt < 2; ++rt)
#pragma unroll
    for (int r = 0; r < 4; ++r) z2r[rt][r] = z2g[rowbase + rt * 16 + g * 4 + r];

  const char* ehb = (const char*)eh + (size_t)k0 * 128;  // 128 B per code
  const char* elb = (const char*)el + (size_t)k0 * 128;
  unsigned boff = (unsigned)(c15 * 128 + g * 16);  // code col + k-chunk offset
  const float* e2p = e2 + k0 + c15;

  float best[2][4];
#pragma unroll
  for (int rt = 0; rt < 2; ++rt)
#pragma unroll
    for (int r = 0; r < 4; ++r) best[rt][r] = 3.4e38f;

  for (int t = 0; t < TS; ++t) {
    s8v bh0 = *(const s8v*)(ehb + boff);
    s8v bh1 = *(const s8v*)(ehb + boff + 64);
    s8v bl0 = *(const s8v*)(elb + boff);
    s8v bl1 = *(const s8v*)(elb + boff + 64);
    float e2v = *e2p;
#pragma unroll
    for (int rt = 0; rt < 2; ++rt) {
      f4 acc = {0.f, 0.f, 0.f, 0.f};
      acc = MFMA(Ah[rt][0], bh0, acc);
      acc = MFMA(Ah[rt][1], bh1, acc);
      acc = MFMA(Al[rt][0], bh0, acc);
      acc = MFMA(Al[rt][1], bh1, acc);
      acc = MFMA(Ah[rt][0], bl0, acc);
      acc = MFMA(Ah[rt][1], bl1, acc);
#pragma unroll
      for (int r = 0; r < 4; ++r) {
        float d = (z2r[rt][r] + e2v) - 2.0f * acc[r];
        best[rt][r] = fminf(best[rt][r], d);
      }
    }
    boff += 2048;  // 16 codes * 128B
    e2p += 16;
  }

  // Cross-lane min within each 16-lane group (rows are group-local).
#pragma unroll
  for (int m = 1; m < 16; m <<= 1) {
#pragma unroll
    for (int rt = 0; rt < 2; ++rt)
#pragma unroll
      for (int r = 0; r < 4; ++r)
        best[rt][r] = fminf(best[rt][r], __shfl_xor(best[rt][r], m));
  }
  if (c15 == 0) {
#pragma unroll
    for (int rt = 0; rt < 2; ++rt)
#pragma unroll
      for (int r = 0; r < 4; ++r)
        aminS[(size_t)s * N + rowbase + rt * 16 + g * 4 + r] = best[rt][r];
  }
}

// Pass 2: identical approx sweep over one K-slice; candidates within the
// GLOBAL band (fmin over slices + 1e-4) get the BIT-EXACT R10 fp32 dist and
// a lexicographic atomicMin on (dist_bits<<32 | code).
__global__ __launch_bounds__(256) void sweep2(const float* __restrict__ z,
                                              const float* __restrict__ emb,
                                              const float* __restrict__ z2g,
                                              const float* __restrict__ e2,
                                              const unsigned short* __restrict__ eh,
                                              const unsigned short* __restrict__ el,
                                              const float* __restrict__ aminS,
                                              unsigned long long* __restrict__ cand) {
  const int tid = threadIdx.x;
  const int lane = tid & 63;
  const int wv = tid >> 6;
  const int g = lane >> 4;
  const int c15 = lane & 15;
  const int rowbase = blockIdx.x * 128 + wv * 32;
  const int s = blockIdx.y;
  const int k0 = s * KSL;

  s8v Ah[2][2], Al[2][2];
#pragma unroll
  for (int rt = 0; rt < 2; ++rt) {
    const float* zrow = z + (size_t)(rowbase + rt * 16 + c15) * D;
#pragma unroll
    for (int c = 0; c < 2; ++c) {
      float4 v0 = *(const float4*)(zrow + c * 32 + g * 8);
      float4 v1 = *(const float4*)(zrow + c * 32 + g * 8 + 4);
      splitbf(v0, v1, Ah[rt][c], Al[rt][c]);
    }
  }
  float z2r[2][4], aband[2][4];
#pragma unroll
  for (int rt = 0; rt < 2; ++rt)
#pragma unroll
    for (int r = 0; r < 4; ++r) {
      int row = rowbase + rt * 16 + g * 4 + r;
      z2r[rt][r] = z2g[row];
      float a = aminS[row];
#pragma unroll
      for (int q = 1; q < SL; ++q) a = fminf(a, aminS[(size_t)q * N + row]);
      aband[rt][r] = a + 1e-4f;  // band >> (approx err + fp32-path err)
    }

  const char* ehb = (const char*)eh + (size_t)k0 * 128;
  const char* elb = (const char*)el + (size_t)k0 * 128;
  unsigned boff = (unsigned)(c15 * 128 + g * 16);
  const float* e2p = e2 + k0 + c15;

  for (int t = 0; t < TS; ++t) {
    s8v bh0 = *(const s8v*)(ehb + boff);
    s8v bh1 = *(const s8v*)(ehb + boff + 64);
    s8v bl0 = *(const s8v*)(elb + boff);
    s8v bl1 = *(const s8v*)(elb + boff + 64);
    float e2v = *e2p;
#pragma unroll
    for (int rt = 0; rt < 2; ++rt) {
      f4 acc = {0.f, 0.f, 0.f, 0.f};
      acc = MFMA(Ah[rt][0], bh0, acc);
      acc = MFMA(Ah[rt][1], bh1, acc);
      acc = MFMA(Al[rt][0], bh0, acc);
      acc = MFMA(Al[rt][1], bh1, acc);
      acc = MFMA(Ah[rt][0], bl0, acc);
      acc = MFMA(Ah[rt][1], bl1, acc);
#pragma unroll
      for (int r = 0; r < 4; ++r) {
        float d = (z2r[rt][r] + e2v) - 2.0f * acc[r];
        if (d <= aband[rt][r]) {
          // Exact fp32 dist, BIT-IDENTICAL to R10's sequence:
          // quad-split partials by d%4, ascending d, (s0+s1)+(s2+s3),
          // dist = (z2 + e2[k]) - 2*dot.
          int code = k0 + t * 16 + c15;
          int row = rowbase + rt * 16 + g * 4 + r;
          const float4* zp = (const float4*)(z + (size_t)row * D);
          const float4* epv = (const float4*)(emb + (size_t)code * D);
          float s0 = 0.f, s1 = 0.f, s2 = 0.f, s3 = 0.f;
#pragma unroll 4
          for (int i = 0; i < 16; ++i) {
            float4 a = zp[i];
            float4 b = epv[i];
            s0 = fmaf(a.x, b.x, s0);
            s1 = fmaf(a.y, b.y, s1);
            s2 = fmaf(a.z, b.z, s2);
            s3 = fmaf(a.w, b.w, s3);
          }
          float dot = (s0 + s1) + (s2 + s3);
          float de = (z2r[rt][r] + e2v) - 2.0f * dot;
          unsigned long long pk =
              ((unsigned long long)__float_as_uint(de) << 32) | (unsigned)code;
          atomicMin(cand + row, pk);  // lexicographic (dist, idx): first-index ties
        }
      }
    }
    boff += 2048;
    e2p += 16;
  }
}

// Epilogue: read winner index, gather/losses/counts/index write (as before).
__global__ __launch_bounds__(256) void vq_epilogue(const float* __restrict__ z,
                                                   const float* __restrict__ emb,
                                                   const unsigned long long* __restrict__ cand,
                                                   float* __restrict__ out,
                                                   int* __restrict__ counts,
                                                   float* __restrict__ loss) {
  __shared__ float red[4];
  const int tid = threadIdx.x;
  const int n = blockIdx.x * 256 + tid;

  int bidx = (int)(unsigned)(cand[n] & 0xFFFFFFFFull);

  out[(size_t)N * D + 3 + n] = (float)bidx;
  atomicAdd(&counts[bidx], 1);

  const float4* zp = (const float4*)(z + (size_t)n * D);
  const float4* qp = (const float4*)(emb + (size_t)bidx * D);
  float4* op = (float4*)(out + (size_t)n * D);
  float lsum = 0.f;
#pragma unroll
  for (int i = 0; i < 16; ++i) {
    float4 q = qp[i];
    float4 zz = zp[i];
    float dx = q.x - zz.x, dy = q.y - zz.y, dz = q.z - zz.z, dw = q.w - zz.w;
    lsum = fmaf(dx, dx, lsum);
    lsum = fmaf(dy, dy, lsum);
    lsum = fmaf(dz, dz, lsum);
    lsum = fmaf(dw, dw, lsum);
    // z_q_st = z + (z_q - z), replicated op-for-op
    float4 r;
    r.x = zz.x + dx; r.y = zz.y + dy; r.z = zz.z + dz; r.w = zz.w + dw;
    op[i] = r;
  }

#pragma unroll
  for (int off = 32; off > 0; off >>= 1) lsum += __shfl_down(lsum, off);
  if ((tid & 63) == 0) red[tid >> 6] = lsum;
  __syncthreads();
  if (tid == 0) atomicAdd(loss, (red[0] + red[1]) + (red[2] + red[3]));
}

__global__ __launch_bounds__(256) void finalize_kernel(const int* __restrict__ counts,
                                                       const float* __restrict__ loss,
                                                       float* __restrict__ out) {
  const int tid = threadIdx.x;
  double ent = 0.0;
  int active = 0;
  for (int k = tid; k < K; k += 256) {
    int c = counts[k];
    float p = (float)c / 65536.0f;
    if (c > 0) active++;
    ent += (double)(p * logf(p + 1e-10f));
  }
#pragma unroll
  for (int off = 32; off > 0; off >>= 1) {
    ent += __shfl_down(ent, off);
    active += __shfl_down(active, off);
  }
  __shared__ double ered[4];
  __shared__ int ared[4];
  if ((tid & 63) == 0) { ered[tid >> 6] = ent; ared[tid >> 6] = active; }
  __syncthreads();
  if (tid == 0) {
    double e = (ered[0] + ered[1]) + (ered[2] + ered[3]);
    int a = (ared[0] + ared[1]) + (ared[2] + ared[3]);
    float mean = *loss / (float)((size_t)N * D);
    float cb = mean;
    float cm = mean;
    float vq = cb + 0.25f * cm;
    size_t base = (size_t)N * D;
    out[base + 0] = vq;
    out[base + 1] = cb;
    out[base + 2] = cm;
    out[base + 3 + N] = (float)exp(-e);
    out[base + 4 + N] = (float)a;
  }
}

extern "C" void kernel_launch(void* const* d_in, const int* in_sizes, int n_in,
                              void* d_out, int out_size, void* d_ws, size_t ws_size,
                              hipStream_t stream) {
  const float* z = (const float*)d_in[0];
  const float* emb = (const float*)d_in[1];
  float* out = (float*)d_out;

  char* w = (char*)d_ws;
  float* e2 = (float*)w;                          w += (size_t)K * sizeof(float);
  int* counts = (int*)w;                          w += (size_t)K * sizeof(int);
  float* loss = (float*)w;                        w += 256;  // keep alignment
  float* z2 = (float*)w;                          w += (size_t)N * sizeof(float);
  float* aminS = (float*)w;                       w += (size_t)SL * N * sizeof(float);
  unsigned long long* cand = (unsigned long long*)w;
                                                  w += (size_t)N * sizeof(unsigned long long);
  unsigned short* eh = (unsigned short*)w;        w += (size_t)K * D * sizeof(unsigned short);
  unsigned short* el = (unsigned short*)w;

  prep_emb<<<K / 256, 256, 0, stream>>>(emb, e2, counts, loss, eh, el);
  prep_z<<<N / 256, 256, 0, stream>>>(z, z2, cand);
  sweep1<<<dim3(N / 128, SL), 256, 0, stream>>>(z, z2, e2, eh, el, aminS);
  sweep2<<<dim3(N / 128, SL), 256, 0, stream>>>(z, emb, z2, e2, eh, el, aminS, cand);
  vq_epilogue<<<N / 256, 256, 0, stream>>>(z, emb, cand, out, counts, loss);
  finalize_kernel<<<1, 256, 0, stream>>>(counts, loss, out);
}

// Round 16
// 351.174 us; speedup vs baseline: 1.8653x; 1.8653x over previous
//
#include <hip/hip_runtime.h>

// VQ-VAE Vector Quantizer: N=65536 rows, K=4096 codes, D=64, fp32.
// R15: coalesced fragment-order B + banked distance-1 prefetch.
// R14 refuted occupancy as the limiter (occ 22->42%, sweep 340us unchanged,
// MfmaUtil 12.5% pinned) -> throughput limit inside the iteration:
// (1) B-loads were 16B/lane at stride-128 = 16 cache lines per instruction
//     (16x TA/line-fill work, L1 100% miss) - a throughput cost more waves
//     cannot hide. Fix: prep writes ehT/elT in MFMA-FRAGMENT ORDER so every
//     sweep load is a coalesced dwordx4 (64 lanes x 16B contiguous).
// (2) loads were consumed same-iteration (serial vmcnt chain). Fix: R7-style
//     banked refill - consume banks in MFMAs, refill from tile t+1, peel last.
// Same bytes reach the same MFMAs -> approx values bit-identical to the
// PASSING R13/R14; band + exact-rescue path unchanged -> identical indices,
// absmax 0 by construction.
//
// out layout (float): [0,N*D) z_q_st | [ND] vq | [ND+1] cb | [ND+2] cm |
//                     [ND+3, ND+3+N) indices | [ND+3+N] perplexity | [ND+4+N] active

constexpr int N = 65536;
constexpr int K = 4096;
constexpr int D = 64;
constexpr int SL = 4;        // K-split for the sweeps
constexpr int KSL = K / SL;  // 1024 codes per slice
constexpr int TS = KSL / 16; // 64 tiles per slice

typedef short s8v __attribute__((ext_vector_type(8)));   // 8 bf16 (4 VGPRs)
typedef float f4 __attribute__((ext_vector_type(4)));    // 4 fp32 acc

#define MFMA(a, b, c) __builtin_amdgcn_mfma_f32_16x16x32_bf16((a), (b), (c), 0, 0, 0)

__device__ inline unsigned bfr(float x) {  // fp32 -> bf16 bits, RNE
  unsigned b = __float_as_uint(x);
  return (b + 0x7FFFu + ((b >> 16) & 1u)) >> 16;
}

__device__ inline void splitbf(const float4 v0, const float4 v1, s8v& hi, s8v& lo) {
  float x[8] = {v0.x, v0.y, v0.z, v0.w, v1.x, v1.y, v1.z, v1.w};
#pragma unroll
  for (int j = 0; j < 8; ++j) {
    unsigned h = bfr(x[j]);
    float hf = __uint_as_float(h << 16);
    unsigned l = bfr(x[j] - hf);
    hi[j] = (short)h;
    lo[j] = (short)l;
  }
}

// prep: e2 (exact quad-split, same as R10), counts=0, loss=0, and bf16x2
// split of emb written in FRAGMENT ORDER:
//   tile t (16 codes), lane l = g*16 + c15:
//   chunk0 (k-elems [g*8,+8) of code t*16+c15) at u16 offset t*1024 + l*8
//   chunk1 (k-elems [32+g*8,+8))             at u16 offset t*1024 + 512 + l*8
__global__ __launch_bounds__(256) void prep_emb(const float* __restrict__ emb,
                                                float* __restrict__ e2,
                                                int* __restrict__ counts,
                                                float* __restrict__ loss,
                                                unsigned short* __restrict__ ehT,
                                                unsigned short* __restrict__ elT) {
  int k = blockIdx.x * 256 + threadIdx.x;
  if (k < K) {
    const float4* ep = (const float4*)(emb + (size_t)k * D);
    unsigned short h[64], l[64];
    float s0 = 0.f, s1 = 0.f, s2 = 0.f, s3 = 0.f;
#pragma unroll
    for (int i = 0; i < 16; ++i) {
      float4 e = ep[i];
      s0 = fmaf(e.x, e.x, s0);
      s1 = fmaf(e.y, e.y, s1);
      s2 = fmaf(e.z, e.z, s2);
      s3 = fmaf(e.w, e.w, s3);
      float xs[4] = {e.x, e.y, e.z, e.w};
#pragma unroll
      for (int c = 0; c < 4; ++c) {
        unsigned hb = bfr(xs[c]);
        h[4 * i + c] = (unsigned short)hb;
        l[4 * i + c] = (unsigned short)bfr(xs[c] - __uint_as_float(hb << 16));
      }
    }
    e2[k] = (s0 + s1) + (s2 + s3);
    counts[k] = 0;

    const int t = k >> 4;
    const int c15 = k & 15;
#pragma unroll
    for (int g = 0; g < 4; ++g) {
      const size_t d0 = (size_t)t * 1024 + (size_t)(g * 16 + c15) * 8;
      const size_t d1 = d0 + 512;
#pragma unroll
      for (int j = 0; j < 8; ++j) {
        ehT[d0 + j] = h[g * 8 + j];
        ehT[d1 + j] = h[32 + g * 8 + j];
        elT[d0 + j] = l[g * 8 + j];
        elT[d1 + j] = l[32 + g * 8 + j];
      }
    }
  }
  if (blockIdx.x == 0 && threadIdx.x == 0) *loss = 0.0f;
}

// prep: z2 per row (exact quad-split, bit-identical to R10's in-kernel z2) + cand init.
__global__ __launch_bounds__(256) void prep_z(const float* __restrict__ z,
                                              float* __restrict__ z2,
                                              unsigned long long* __restrict__ cand) {
  int n = blockIdx.x * 256 + threadIdx.x;
  const float4* zp = (const float4*)(z + (size_t)n * D);
  float s0 = 0.f, s1 = 0.f, s2 = 0.f, s3 = 0.f;
#pragma unroll
  for (int i = 0; i < 16; ++i) {
    float4 v = zp[i];
    s0 = fmaf(v.x, v.x, s0);
    s1 = fmaf(v.y, v.y, s1);
    s2 = fmaf(v.z, v.z, s2);
    s3 = fmaf(v.w, v.w, s3);
  }
  z2[n] = (s0 + s1) + (s2 + s3);
  cand[n] = 0x7F800000FFFFFFFFull;  // (+inf bits, idx max)
}

// Pass 1: approx dist sweep via MFMA over one K-slice; per-(slice,row) min.
// Block = 4 waves; wave owns 2 row-tiles (32 rows); grid = (N/128, SL).
__global__ __launch_bounds__(256) void sweep1(const float* __restrict__ z,
                                              const float* __restrict__ z2g,
                                              const float* __restrict__ e2,
                                              const unsigned short* __restrict__ ehT,
                                              const unsigned short* __restrict__ elT,
                                              float* __restrict__ aminS) {
  const int tid = threadIdx.x;
  const int lane = tid & 63;
  const int wv = tid >> 6;
  const int g = lane >> 4;
  const int c15 = lane & 15;
  const int rowbase = blockIdx.x * 128 + wv * 32;
  const int s = blockIdx.y;
  const int k0 = s * KSL;

  // A fragments: z rows (lane&15 selects row), k = 32c + 8g + j, bf16x2 split.
  s8v Ah[2][2], Al[2][2];
#pragma unroll
  for (int rt = 0; rt < 2; ++rt) {
    const float* zrow = z + (size_t)(rowbase + rt * 16 + c15) * D;
#pragma unroll
    for (int c = 0; c < 2; ++c) {
      float4 v0 = *(const float4*)(zrow + c * 32 + g * 8);
      float4 v1 = *(const float4*)(zrow + c * 32 + g * 8 + 4);
      splitbf(v0, v1, Ah[rt][c], Al[rt][c]);
    }
  }
  float z2r[2][4];
#pragma unroll
  for (int rt = 0; rt < 2; ++rt)
#pragma unroll
    for (int r = 0; r < 4; ++r) z2r[rt][r] = z2g[rowbase + rt * 16 + g * 4 + r];

  // Fragment-order streams: tile = 128 s8v (2KB); chunk1 at +64.
  const s8v* bh = (const s8v*)ehT + (size_t)(s * TS) * 128;
  const s8v* bl = (const s8v*)elT + (size_t)(s * TS) * 128;
  const float* e2p = e2 + k0 + c15;

  // Prologue: tile 0 into banks (coalesced dwordx4 each).
  s8v bh0 = bh[lane], bh1 = bh[64 + lane];
  s8v bl0 = bl[lane], bl1 = bl[64 + lane];
  float e2cur = *e2p;

  float best[2][4];
#pragma unroll
  for (int rt = 0; rt < 2; ++rt)
#pragma unroll
    for (int r = 0; r < 4; ++r) best[rt][r] = 3.4e38f;

  for (int t = 0; t < TS; ++t) {
#pragma unroll
    for (int rt = 0; rt < 2; ++rt) {
      f4 acc = {0.f, 0.f, 0.f, 0.f};
      acc = MFMA(Ah[rt][0], bh0, acc);
      acc = MFMA(Ah[rt][1], bh1, acc);
      acc = MFMA(Al[rt][0], bh0, acc);
      acc = MFMA(Al[rt][1], bh1, acc);
      acc = MFMA(Ah[rt][0], bl0, acc);
      acc = MFMA(Ah[rt][1], bl1, acc);
#pragma unroll
      for (int r = 0; r < 4; ++r) {
        float d = (z2r[rt][r] + e2cur) - 2.0f * acc[r];
        best[rt][r] = fminf(best[rt][r], d);
      }
    }
    // Banked refill from tile t+1 (WAR after consumption; compiler manages waits).
    if (t < TS - 1) {
      bh += 128; bl += 128; e2p += 16;
      bh0 = bh[lane]; bh1 = bh[64 + lane];
      bl0 = bl[lane]; bl1 = bl[64 + lane];
      e2cur = *e2p;
    }
  }

  // Cross-lane min within each 16-lane group (rows are group-local).
#pragma unroll
  for (int m = 1; m < 16; m <<= 1) {
#pragma unroll
    for (int rt = 0; rt < 2; ++rt)
#pragma unroll
      for (int r = 0; r < 4; ++r)
        best[rt][r] = fminf(best[rt][r], __shfl_xor(best[rt][r], m));
  }
  if (c15 == 0) {
#pragma unroll
    for (int rt = 0; rt < 2; ++rt)
#pragma unroll
      for (int r = 0; r < 4; ++r)
        aminS[(size_t)s * N + rowbase + rt * 16 + g * 4 + r] = best[rt][r];
  }
}

// Pass 2: identical approx sweep over one K-slice; candidates within the
// GLOBAL band (fmin over slices + 1e-4) get the BIT-EXACT R10 fp32 dist and
// a lexicographic atomicMin on (dist_bits<<32 | code).
__global__ __launch_bounds__(256) void sweep2(const float* __restrict__ z,
                                              const float* __restrict__ emb,
                                              const float* __restrict__ z2g,
                                              const float* __restrict__ e2,
                                              const unsigned short* __restrict__ ehT,
                                              const unsigned short* __restrict__ elT,
                                              const float* __restrict__ aminS,
                                              unsigned long long* __restrict__ cand) {
  const int tid = threadIdx.x;
  const int lane = tid & 63;
  const int wv = tid >> 6;
  const int g = lane >> 4;
  const int c15 = lane & 15;
  const int rowbase = blockIdx.x * 128 + wv * 32;
  const int s = blockIdx.y;
  const int k0 = s * KSL;

  s8v Ah[2][2], Al[2][2];
#pragma unroll
  for (int rt = 0; rt < 2; ++rt) {
    const float* zrow = z + (size_t)(rowbase + rt * 16 + c15) * D;
#pragma unroll
    for (int c = 0; c < 2; ++c) {
      float4 v0 = *(const float4*)(zrow + c * 32 + g * 8);
      float4 v1 = *(const float4*)(zrow + c * 32 + g * 8 + 4);
      splitbf(v0, v1, Ah[rt][c], Al[rt][c]);
    }
  }
  float z2r[2][4], aband[2][4];
#pragma unroll
  for (int rt = 0; rt < 2; ++rt)
#pragma unroll
    for (int r = 0; r < 4; ++r) {
      int row = rowbase + rt * 16 + g * 4 + r;
      z2r[rt][r] = z2g[row];
      float a = aminS[row];
#pragma unroll
      for (int q = 1; q < SL; ++q) a = fminf(a, aminS[(size_t)q * N + row]);
      aband[rt][r] = a + 1e-4f;  // band >> (approx err + fp32-path err)
    }

  const s8v* bh = (const s8v*)ehT + (size_t)(s * TS) * 128;
  const s8v* bl = (const s8v*)elT + (size_t)(s * TS) * 128;
  const float* e2p = e2 + k0 + c15;

  s8v bh0 = bh[lane], bh1 = bh[64 + lane];
  s8v bl0 = bl[lane], bl1 = bl[64 + lane];
  float e2cur = *e2p;

  for (int t = 0; t < TS; ++t) {
#pragma unroll
    for (int rt = 0; rt < 2; ++rt) {
      f4 acc = {0.f, 0.f, 0.f, 0.f};
      acc = MFMA(Ah[rt][0], bh0, acc);
      acc = MFMA(Ah[rt][1], bh1, acc);
      acc = MFMA(Al[rt][0], bh0, acc);
      acc = MFMA(Al[rt][1], bh1, acc);
      acc = MFMA(Ah[rt][0], bl0, acc);
      acc = MFMA(Ah[rt][1], bl1, acc);
#pragma unroll
      for (int r = 0; r < 4; ++r) {
        float d = (z2r[rt][r] + e2cur) - 2.0f * acc[r];
        if (d <= aband[rt][r]) {
          // Exact fp32 dist, BIT-IDENTICAL to R10's sequence:
          // quad-split partials by d%4, ascending d, (s0+s1)+(s2+s3),
          // dist = (z2 + e2[k]) - 2*dot.
          int code = k0 + t * 16 + c15;
          int row = rowbase + rt * 16 + g * 4 + r;
          const float4* zp = (const float4*)(z + (size_t)row * D);
          const float4* epv = (const float4*)(emb + (size_t)code * D);
          float s0 = 0.f, s1 = 0.f, s2 = 0.f, s3 = 0.f;
#pragma unroll 4
          for (int i = 0; i < 16; ++i) {
            float4 a = zp[i];
            float4 b = epv[i];
            s0 = fmaf(a.x, b.x, s0);
            s1 = fmaf(a.y, b.y, s1);
            s2 = fmaf(a.z, b.z, s2);
            s3 = fmaf(a.w, b.w, s3);
          }
          float dot = (s0 + s1) + (s2 + s3);
          float de = (z2r[rt][r] + e2cur) - 2.0f * dot;
          unsigned long long pk =
              ((unsigned long long)__float_as_uint(de) << 32) | (unsigned)code;
          atomicMin(cand + row, pk);  // lexicographic (dist, idx): first-index ties
        }
      }
    }
    if (t < TS - 1) {
      bh += 128; bl += 128; e2p += 16;
      bh0 = bh[lane]; bh1 = bh[64 + lane];
      bl0 = bl[lane]; bl1 = bl[64 + lane];
      e2cur = *e2p;
    }
  }
}

// Epilogue: read winner index, gather/losses/counts/index write (as before).
__global__ __launch_bounds__(256) void vq_epilogue(const float* __restrict__ z,
                                                   const float* __restrict__ emb,
                                                   const unsigned long long* __restrict__ cand,
                                                   float* __restrict__ out,
                                                   int* __restrict__ counts,
                                                   float* __restrict__ loss) {
  __shared__ float red[4];
  const int tid = threadIdx.x;
  const int n = blockIdx.x * 256 + tid;

  int bidx = (int)(unsigned)(cand[n] & 0xFFFFFFFFull);

  out[(size_t)N * D + 3 + n] = (float)bidx;
  atomicAdd(&counts[bidx], 1);

  const float4* zp = (const float4*)(z + (size_t)n * D);
  const float4* qp = (const float4*)(emb + (size_t)bidx * D);
  float4* op = (float4*)(out + (size_t)n * D);
  float lsum = 0.f;
#pragma unroll
  for (int i = 0; i < 16; ++i) {
    float4 q = qp[i];
    float4 zz = zp[i];
    float dx = q.x - zz.x, dy = q.y - zz.y, dz = q.z - zz.z, dw = q.w - zz.w;
    lsum = fmaf(dx, dx, lsum);
    lsum = fmaf(dy, dy, lsum);
    lsum = fmaf(dz, dz, lsum);
    lsum = fmaf(dw, dw, lsum);
    // z_q_st = z + (z_q - z), replicated op-for-op
    float4 r;
    r.x = zz.x + dx; r.y = zz.y + dy; r.z = zz.z + dz; r.w = zz.w + dw;
    op[i] = r;
  }

#pragma unroll
  for (int off = 32; off > 0; off >>= 1) lsum += __shfl_down(lsum, off);
  if ((tid & 63) == 0) red[tid >> 6] = lsum;
  __syncthreads();
  if (tid == 0) atomicAdd(loss, (red[0] + red[1]) + (red[2] + red[3]));
}

__global__ __launch_bounds__(256) void finalize_kernel(const int* __restrict__ counts,
                                                       const float* __restrict__ loss,
                                                       float* __restrict__ out) {
  const int tid = threadIdx.x;
  double ent = 0.0;
  int active = 0;
  for (int k = tid; k < K; k += 256) {
    int c = counts[k];
    float p = (float)c / 65536.0f;
    if (c > 0) active++;
    ent += (double)(p * logf(p + 1e-10f));
  }
#pragma unroll
  for (int off = 32; off > 0; off >>= 1) {
    ent += __shfl_down(ent, off);
    active += __shfl_down(active, off);
  }
  __shared__ double ered[4];
  __shared__ int ared[4];
  if ((tid & 63) == 0) { ered[tid >> 6] = ent; ared[tid >> 6] = active; }
  __syncthreads();
  if (tid == 0) {
    double e = (ered[0] + ered[1]) + (ered[2] + ered[3]);
    int a = (ared[0] + ared[1]) + (ared[2] + ared[3]);
    float mean = *loss / (float)((size_t)N * D);
    float cb = mean;
    float cm = mean;
    float vq = cb + 0.25f * cm;
    size_t base = (size_t)N * D;
    out[base + 0] = vq;
    out[base + 1] = cb;
    out[base + 2] = cm;
    out[base + 3 + N] = (float)exp(-e);
    out[base + 4 + N] = (float)a;
  }
}

extern "C" void kernel_launch(void* const* d_in, const int* in_sizes, int n_in,
                              void* d_out, int out_size, void* d_ws, size_t ws_size,
                              hipStream_t stream) {
  const float* z = (const float*)d_in[0];
  const float* emb = (const float*)d_in[1];
  float* out = (float*)d_out;

  char* w = (char*)d_ws;
  float* e2 = (float*)w;                          w += (size_t)K * sizeof(float);
  int* counts = (int*)w;                          w += (size_t)K * sizeof(int);
  float* loss = (float*)w;                        w += 256;  // keep alignment
  float* z2 = (float*)w;                          w += (size_t)N * sizeof(float);
  float* aminS = (float*)w;                       w += (size_t)SL * N * sizeof(float);
  unsigned long long* cand = (unsigned long long*)w;
                                                  w += (size_t)N * sizeof(unsigned long long);
  unsigned short* ehT = (unsigned short*)w;       w += (size_t)K * D * sizeof(unsigned short);
  unsigned short* elT = (unsigned short*)w;

  prep_emb<<<K / 256, 256, 0, stream>>>(emb, e2, counts, loss, ehT, elT);
  prep_z<<<N / 256, 256, 0, stream>>>(z, z2, cand);
  sweep1<<<dim3(N / 128, SL), 256, 0, stream>>>(z, z2, e2, ehT, elT, aminS);
  sweep2<<<dim3(N / 128, SL), 256, 0, stream>>>(z, emb, z2, e2, ehT, elT, aminS, cand);
  vq_epilogue<<<N / 256, 256, 0, stream>>>(z, emb, cand, out, counts, loss);
  finalize_kernel<<<1, 256, 0, stream>>>(counts, loss, out);
}